// Round 3
// baseline (4198.330 us; speedup 1.0000x reference)
//
#include <hip/hip_runtime.h>
#include <hip/hip_bf16.h>

#define GG 512
#define NMAX 256
#define EE 1024
#define HH 3
#define EMB 256
#define NEDGE 1280   // EE + NMAX
#define NEG 0.2f

// ---------------- prep kernels (per layer, tiny, run once) ----------------
__global__ void k_prep_wa(const float* __restrict__ W, const float* __restrict__ asrc,
                          const float* __restrict__ adst, float* __restrict__ wa_s,
                          float* __restrict__ wa_d, int f) {
  int t = blockIdx.x * blockDim.x + threadIdx.x;
  int tot = HH * f;
  if (t >= 2 * tot) return;
  int which = t / tot;
  int r = t - which * tot;
  int hd = r / f, ff = r - hd * f;
  const float* a = which ? adst : asrc;
  float s = 0.f;
  for (int c = 0; c < EMB; ++c)
    s += a[hd * EMB + c] * W[(size_t)(hd * EMB + c) * f + ff];
  (which ? wa_d : wa_s)[r] = s;
}

__global__ void k_prep_mcat(const float* __restrict__ W, const float* __restrict__ htw,
                            float* __restrict__ mcat, int f) {
  int t = blockIdx.x * blockDim.x + threadIdx.x;
  if (t >= 3 * f * EMB) return;
  int row = t / EMB, j = t - row * EMB;
  int hd = row / f, ff = row - hd * f;
  float s = 0.f;
  for (int c = 0; c < EMB; ++c)
    s += htw[(size_t)j * (HH * EMB) + hd * EMB + c] * W[(size_t)(hd * EMB + c) * f + ff];
  mcat[(size_t)row * EMB + j] = s;
}

__global__ void k_prep_bb(const float* __restrict__ b, const float* __restrict__ htw,
                          const float* __restrict__ htb, float* __restrict__ bb) {
  int j = threadIdx.x;
  float s = htb[j];
  for (int k = 0; k < HH * EMB; ++k) s += b[k] * htw[(size_t)j * (HH * EMB) + k];
  bb[j] = s;
}

__global__ void k_prep_pnorm(const float* __restrict__ p, double* __restrict__ pnorm) {
  __shared__ double sh[256];
  int t = threadIdx.x;
  double v = (double)p[t];
  sh[t] = v * v;
  __syncthreads();
  for (int s = 128; s > 0; s >>= 1) { if (t < s) sh[t] += sh[t + s]; __syncthreads(); }
  if (t == 0) pnorm[0] = sqrt(sh[0]);
}

// ---------------- per-chunk edge init ----------------
__global__ void k_initedges(const int* __restrict__ s_in, const int* __restrict__ d_in_,
                            int* __restrict__ es, int* __restrict__ ed,
                            int* __restrict__ em, int gc) {
  int t = blockIdx.x * blockDim.x + threadIdx.x;
  if (t >= gc * EE) return;
  es[t] = s_in[t]; ed[t] = d_in_[t]; em[t] = 1;
}

// ---------------- attention coefficients a_s, a_d ----------------
__global__ __launch_bounds__(256) void k_attn(
    const float* __restrict__ x, const float* __restrict__ wa_s,
    const float* __restrict__ wa_d, float* __restrict__ a_s,
    float* __restrict__ a_d, int gc, int n_in, int f) {
  int t = blockIdx.x * blockDim.x + threadIdx.x;
  if (t >= gc * n_in) return;
  int g = t / n_in, i = t - g * n_in;
  const float* xr = x + ((size_t)g * NMAX + i) * f;
  float s0 = 0, s1 = 0, s2 = 0, d0 = 0, d1 = 0, d2 = 0;
  for (int c = 0; c < f; ++c) {
    float xv = xr[c];
    s0 += xv * wa_s[0 * f + c]; s1 += xv * wa_s[1 * f + c]; s2 += xv * wa_s[2 * f + c];
    d0 += xv * wa_d[0 * f + c]; d1 += xv * wa_d[1 * f + c]; d2 += xv * wa_d[2 * f + c];
  }
  float* as = a_s + ((size_t)g * NMAX + i) * HH;
  float* ad = a_d + ((size_t)g * NMAX + i) * HH;
  as[0] = s0; as[1] = s1; as[2] = s2; ad[0] = d0; ad[1] = d1; ad[2] = d2;
}

// ---------------- edge logits (valid edges + self loops) ----------------
__global__ __launch_bounds__(256) void k_logit(
    const int* __restrict__ es, const int* __restrict__ ed,
    const int* __restrict__ em, const float* __restrict__ a_s,
    const float* __restrict__ a_d, float* __restrict__ lg, int gc, int n_in) {
  int etot = EE + n_in;
  int t = blockIdx.x * blockDim.x + threadIdx.x;
  if (t >= gc * etot) return;
  int g = t / etot, e = t - g * etot;
  int s, d, v;
  if (e < EE) { s = es[g * EE + e]; d = ed[g * EE + e]; v = em[g * EE + e]; }
  else { s = d = e - EE; v = 1; }
  if (!v) return;
  const float* as = a_s + ((size_t)g * NMAX + s) * HH;
  const float* ad = a_d + ((size_t)g * NMAX + d) * HH;
  float* o = lg + ((size_t)g * NEDGE + e) * HH;
#pragma unroll
  for (int hd = 0; hd < HH; ++hd) {
    float lv = as[hd] + ad[hd];
    o[hd] = lv > 0.f ? lv : NEG * lv;
  }
}

// ---------------- deterministic CSR by destination (one block per graph) ----------------
__global__ void k_csr(const int* __restrict__ ed, const int* __restrict__ em,
                      int* __restrict__ coff, int* __restrict__ elist, int n_in) {
  __shared__ unsigned short sdst[NEDGE];
  __shared__ unsigned char sval[NEDGE];
  __shared__ int cnt[257];
  int g = blockIdx.x, tid = threadIdx.x;
  int etot = EE + n_in;
  cnt[tid] = 0;
  if (tid == 0) cnt[256] = 0;
  __syncthreads();
  for (int e = tid; e < etot; e += 256) {
    int d, v;
    if (e < EE) { d = ed[g * EE + e]; v = em[g * EE + e]; }
    else { d = e - EE; v = 1; }
    sdst[e] = (unsigned short)d; sval[e] = (unsigned char)v;
    if (v) atomicAdd(&cnt[d], 1);
  }
  __syncthreads();
  if (tid == 0) {
    int run = 0;
    for (int i = 0; i < n_in; ++i) {
      int c = cnt[i]; cnt[i] = run; coff[g * 257 + i] = run; run += c;
    }
    coff[g * 257 + n_in] = run;
  }
  __syncthreads();
  if (tid < n_in) {
    int pos = cnt[tid];
    for (int e = 0; e < etot; ++e) {
      if (sval[e] && sdst[e] == (unsigned short)tid) elist[g * NEDGE + pos++] = e;
    }
  }
}

// ---------------- per-destination softmax + feature aggregation (one wave per dst) -----
__global__ __launch_bounds__(256) void k_gather(
    const float* __restrict__ x, const float* __restrict__ lg,
    const int* __restrict__ es, const int* __restrict__ elist,
    const int* __restrict__ coff, float* __restrict__ agg,
    int gc, int n_in, int f) {
  int wid = (blockIdx.x * blockDim.x + threadIdx.x) >> 6;
  int lane = threadIdx.x & 63;
  if (wid >= gc * n_in) return;
  int g = wid / n_in, dst = wid - g * n_in;
  int o0 = coff[g * 257 + dst], o1 = coff[g * 257 + dst + 1];
  float m0 = -1e30f, m1 = -1e30f, m2 = -1e30f;
  for (int t = o0; t < o1; ++t) {
    int e = elist[g * NEDGE + t];
    const float* l = lg + ((size_t)g * NEDGE + e) * HH;
    m0 = fmaxf(m0, l[0]); m1 = fmaxf(m1, l[1]); m2 = fmaxf(m2, l[2]);
  }
  float den0 = 0, den1 = 0, den2 = 0;
  float acc[HH][4];
#pragma unroll
  for (int hd = 0; hd < HH; ++hd)
#pragma unroll
    for (int j = 0; j < 4; ++j) acc[hd][j] = 0.f;
  int vpl = (f + 63) >> 6;
  for (int t = o0; t < o1; ++t) {
    int e = elist[g * NEDGE + t];
    const float* l = lg + ((size_t)g * NEDGE + e) * HH;
    float w0 = expf(l[0] - m0), w1 = expf(l[1] - m1), w2 = expf(l[2] - m2);
    den0 += w0; den1 += w1; den2 += w2;
    int src = e < EE ? es[g * EE + e] : (e - EE);
    const float* xr = x + ((size_t)g * NMAX + src) * f;
    for (int j = 0; j < vpl; ++j) {
      int c = lane + (j << 6);
      float xv = (c < f) ? xr[c] : 0.f;
      acc[0][j] += w0 * xv; acc[1][j] += w1 * xv; acc[2][j] += w2 * xv;
    }
  }
  float* ar = agg + ((size_t)g * n_in + dst) * (HH * f);
  float r0 = 1.f / den0, r1 = 1.f / den1, r2 = 1.f / den2;
  for (int j = 0; j < vpl; ++j) {
    int c = lane + (j << 6);
    if (c < f) {
      ar[0 * f + c] = acc[0][j] * r0;
      ar[1 * f + c] = acc[1][j] * r1;
      ar[2 * f + c] = acc[2][j] * r2;
    }
  }
}

// ---------------- fp32 GEMM: Xout[(g*NMAX+ii)*EMB] = agg[Mrows,K] @ Mcat[K,256] + bb ---
__global__ __launch_bounds__(256) void k_gemm(
    const float* __restrict__ A, const float* __restrict__ B,
    const float* __restrict__ bias, float* __restrict__ Xout,
    int Mrows, int K, int n_in) {
  __shared__ float As[16][64];
  __shared__ float Bs[16][64];
  int tid = threadIdx.x;
  int tx = tid & 15, ty = tid >> 4;
  int row0 = blockIdx.x * 64, col0 = blockIdx.y * 64;
  float acc[4][4] = {};
  for (int k0 = 0; k0 < K; k0 += 16) {
    {
      int m = tid >> 2, kq = (tid & 3) << 2;
      int row = row0 + m;
#pragma unroll
      for (int q = 0; q < 4; ++q) {
        int kk = kq + q;
        float v = 0.f;
        if (row < Mrows && (k0 + kk) < K) v = A[(size_t)row * K + k0 + kk];
        As[kk][m] = v;
      }
    }
    {
      int kk = tid >> 4, n4 = (tid & 15) << 2;
#pragma unroll
      for (int q = 0; q < 4; ++q) {
        float v = 0.f;
        if (k0 + kk < K) v = B[(size_t)(k0 + kk) * EMB + col0 + n4 + q];
        Bs[kk][n4 + q] = v;
      }
    }
    __syncthreads();
#pragma unroll
    for (int kk = 0; kk < 16; ++kk) {
      float4 av = *(const float4*)&As[kk][ty << 2];
      float4 bv = *(const float4*)&Bs[kk][tx << 2];
      float a[4] = {av.x, av.y, av.z, av.w};
      float b[4] = {bv.x, bv.y, bv.z, bv.w};
#pragma unroll
      for (int i = 0; i < 4; ++i)
#pragma unroll
        for (int j = 0; j < 4; ++j) acc[i][j] += a[i] * b[j];
    }
    __syncthreads();
  }
#pragma unroll
  for (int i = 0; i < 4; ++i) {
    int r = row0 + (ty << 2) + i;
    if (r >= Mrows) continue;
    int g = r / n_in, ii = r - g * n_in;
    float* o = Xout + ((size_t)g * NMAX + ii) * EMB + col0 + (tx << 2);
#pragma unroll
    for (int j = 0; j < 4; ++j) o[j] = acc[i][j] + bias[col0 + (tx << 2) + j];
  }
}

// ---------------- TopK pool + readout + edge remap (one block per chunk-graph) --------
__global__ void k_pool(const float* __restrict__ xin, const float* __restrict__ p,
                       const double* __restrict__ pnorm, float* __restrict__ xout,
                       int* __restrict__ es, int* __restrict__ ed, int* __restrict__ em,
                       float* __restrict__ z, int n_in, int k, int g0) {
  __shared__ unsigned long long keys[256];
  __shared__ float ssc[256];
  __shared__ int inv[256];
  int g = blockIdx.x, tid = threadIdx.x;
  double pn = pnorm[0];
  float sc = -3e38f;
  if (tid < n_in) {
    const float* xr = xin + ((size_t)g * NMAX + tid) * EMB;
    double s = 0.0;
    for (int c = 0; c < EMB; ++c) s += (double)xr[c] * (double)p[c];
    sc = (float)tanh(s / pn);
  }
  ssc[tid] = sc;
  unsigned int u = __float_as_uint(sc);
  unsigned int ord = (u & 0x80000000u) ? ~u : (u | 0x80000000u);
  unsigned long long key = ((unsigned long long)(~ord) << 32) | (unsigned int)tid;
  if (tid >= n_in) key = 0xFFFFFFFF00000000ull | (unsigned int)tid;
  keys[tid] = key;
  __syncthreads();
  for (int kk = 2; kk <= 256; kk <<= 1) {
    for (int j = kk >> 1; j > 0; j >>= 1) {
      int ixj = tid ^ j;
      if (ixj > tid) {
        unsigned long long a = keys[tid], b = keys[ixj];
        bool up = ((tid & kk) == 0);
        if (up ? (a > b) : (a < b)) { keys[tid] = b; keys[ixj] = a; }
      }
      __syncthreads();
    }
  }
  inv[tid] = -1;
  __syncthreads();
  if (tid < k) inv[(int)(keys[tid] & 0xFFFFu)] = tid;
  __syncthreads();
  float mx = -3e38f, sm = 0.f;
  for (int j = 0; j < k; ++j) {
    int pi = (int)(keys[j] & 0xFFFFu);
    float val = ssc[pi];
    float v = xin[((size_t)g * NMAX + pi) * EMB + tid] * val;
    xout[((size_t)g * NMAX + j) * EMB + tid] = v;
    mx = fmaxf(mx, v);
    sm += v;
  }
  z[(size_t)(g0 + g) * (2 * EMB) + tid] += mx;
  z[(size_t)(g0 + g) * (2 * EMB) + EMB + tid] += sm / (float)k;
  for (int e = tid; e < EE; e += 256) {
    int s = es[g * EE + e], d = ed[g * EE + e], m = em[g * EE + e];
    int ns = inv[s], nd = inv[d];
    int nm = (m && ns >= 0 && nd >= 0) ? 1 : 0;
    es[g * EE + e] = ns < 0 ? 0 : ns;
    ed[g * EE + e] = nd < 0 ? 0 : nd;
    em[g * EE + e] = nm;
  }
}

// ---------------- final MLP ----------------
__global__ void k_mlp(const float* __restrict__ z, const float* __restrict__ l1w,
                      const float* __restrict__ l1b, const float* __restrict__ l2w,
                      const float* __restrict__ l2b, float* __restrict__ out) {
  __shared__ float zs[512];
  __shared__ float h1[256];
  int g = blockIdx.x, tid = threadIdx.x;
  zs[tid] = z[(size_t)g * 512 + tid];
  zs[256 + tid] = z[(size_t)g * 512 + 256 + tid];
  __syncthreads();
  float s = l1b[tid];
  for (int c = 0; c < 512; ++c) s += zs[c] * l1w[(size_t)tid * 512 + c];
  h1[tid] = s > 0.f ? s : 0.f;
  __syncthreads();
  if (tid < 2) {
    float o = l2b[tid];
    for (int c = 0; c < 256; ++c) o += h1[c] * l2w[(size_t)tid * 256 + c];
    out[g * 2 + tid] = o;
  }
}

extern "C" void kernel_launch(void* const* d_in, const int* in_sizes, int n_in_cnt,
                              void* d_out, int out_size, void* d_ws, size_t ws_size,
                              hipStream_t stream) {
  (void)in_sizes; (void)n_in_cnt; (void)out_size;
  const float* x0 = (const float*)d_in[0];
  const int* e_src = (const int*)d_in[1];
  const int* e_dst = (const int*)d_in[2];
  struct LP { const float *W, *as, *ad, *b, *hw, *hb, *p; int f, nin, nout; };
  LP L[3];
  for (int l = 0; l < 3; ++l) {
    int base = 3 + l * 7;
    L[l].W  = (const float*)d_in[base + 0];
    L[l].as = (const float*)d_in[base + 1];
    L[l].ad = (const float*)d_in[base + 2];
    L[l].b  = (const float*)d_in[base + 3];
    L[l].hw = (const float*)d_in[base + 4];
    L[l].hb = (const float*)d_in[base + 5];
    L[l].p  = (const float*)d_in[base + 6];
  }
  L[0].f = 30;  L[1].f = 256; L[2].f = 256;
  L[0].nin = 256; L[0].nout = 205;
  L[1].nin = 205; L[1].nout = 164;
  L[2].nin = 164; L[2].nout = 132;
  const float* l1w = (const float*)d_in[24];
  const float* l1b = (const float*)d_in[25];
  const float* l2w = (const float*)d_in[26];
  const float* l2b = (const float*)d_in[27];
  float* out = (float*)d_out;

  char* w = (char*)d_ws;
  char* wend = w + ws_size;
  auto alloc = [&](size_t bytes) {
    char* r = w; w += (bytes + 255) & ~(size_t)255; return r;
  };
  // ---- fixed buffers ----
  float*  z    = (float*)alloc((size_t)GG * 512 * 4);
  float*  wa_s[3]; float* wa_d[3]; float* mcat[3]; float* bbv[3];
  for (int l = 0; l < 3; ++l) {
    wa_s[l] = (float*)alloc((size_t)HH * 256 * 4);
    wa_d[l] = (float*)alloc((size_t)HH * 256 * 4);
    mcat[l] = (float*)alloc((size_t)HH * 256 * EMB * 4);
    bbv[l]  = (float*)alloc((size_t)EMB * 4);
  }
  double* pnm = (double*)alloc(256);

  // ---- adaptive chunk size ----
  size_t fixed_used = (size_t)(w - (char*)d_ws);
  size_t per_g = 0;
  {
    auto pad = [](size_t b) { return (b + 255) & ~(size_t)255; };
    per_g = pad((size_t)NMAX * EMB * 4) * 2          // xA, xB
          + pad((size_t)NMAX * HH * EMB * 4)         // agg (256*768 f32)
          + pad((size_t)NMAX * HH * 4) * 2           // a_s, a_d
          + pad((size_t)NEDGE * HH * 4)              // lg
          + pad((size_t)EE * 4) * 3                  // es, ed, em
          + pad((size_t)257 * 4)                     // coff
          + pad((size_t)NEDGE * 4);                  // elist
    per_g += 11 * 256;                               // alignment slop
  }
  size_t avail = (ws_size > fixed_used + 65536) ? (ws_size - fixed_used - 65536) : 0;
  int Gc = (int)(avail / per_g);
  if (Gc > GG) Gc = GG;
  if (Gc < 1) Gc = 1;

  // ---- per-chunk buffers (sized for Gc graphs) ----
  float* xA   = (float*)alloc((size_t)Gc * NMAX * EMB * 4);
  float* xB   = (float*)alloc((size_t)Gc * NMAX * EMB * 4);
  float* agg  = (float*)alloc((size_t)Gc * NMAX * HH * EMB * 4);
  float* a_s  = (float*)alloc((size_t)Gc * NMAX * HH * 4);
  float* a_d  = (float*)alloc((size_t)Gc * NMAX * HH * 4);
  float* lg   = (float*)alloc((size_t)Gc * NEDGE * HH * 4);
  int*   es   = (int*)alloc((size_t)Gc * EE * 4);
  int*   ed   = (int*)alloc((size_t)Gc * EE * 4);
  int*   em   = (int*)alloc((size_t)Gc * EE * 4);
  int*   coff = (int*)alloc((size_t)Gc * 257 * 4);
  int*   elist= (int*)alloc((size_t)Gc * NEDGE * 4);
  if (w > wend) return;  // should not happen; avoid OOB launches entirely

  (void)hipMemsetAsync(z, 0, (size_t)GG * 512 * 4, stream);

  // ---- per-layer prep (once) ----
  for (int l = 0; l < 3; ++l) {
    int f = L[l].f;
    k_prep_wa<<<(2 * HH * f + 255) / 256, 256, 0, stream>>>(L[l].W, L[l].as, L[l].ad, wa_s[l], wa_d[l], f);
    k_prep_mcat<<<(3 * f * EMB + 255) / 256, 256, 0, stream>>>(L[l].W, L[l].hw, mcat[l], f);
    k_prep_bb<<<1, 256, 0, stream>>>(L[l].b, L[l].hw, L[l].hb, bbv[l]);
    k_prep_pnorm<<<1, 256, 0, stream>>>(L[l].p, pnm + l);
  }

  // ---- chunked pipeline over graphs ----
  for (int g0 = 0; g0 < GG; g0 += Gc) {
    int gc = (GG - g0 < Gc) ? (GG - g0) : Gc;
    { int tot = gc * EE;
      k_initedges<<<(tot + 255) / 256, 256, 0, stream>>>(e_src + (size_t)g0 * EE, e_dst + (size_t)g0 * EE, es, ed, em, gc); }
    const float* xin = x0 + (size_t)g0 * NMAX * 30;  // layer-0 input (f=30)
    for (int l = 0; l < 3; ++l) {
      int f = L[l].f, nin = L[l].nin, nout = L[l].nout;
      k_attn<<<(gc * nin + 255) / 256, 256, 0, stream>>>(xin, wa_s[l], wa_d[l], a_s, a_d, gc, nin, f);
      { int tot = gc * (EE + nin);
        k_logit<<<(tot + 255) / 256, 256, 0, stream>>>(es, ed, em, a_s, a_d, lg, gc, nin); }
      k_csr<<<gc, 256, 0, stream>>>(ed, em, coff, elist, nin);
      { int waves = gc * nin;
        k_gather<<<(waves * 64 + 255) / 256, 256, 0, stream>>>(xin, lg, es, elist, coff, agg, gc, nin, f); }
      { int Mrows = gc * nin;
        dim3 gemm_grid((Mrows + 63) / 64, EMB / 64);
        k_gemm<<<gemm_grid, 256, 0, stream>>>(agg, mcat[l], bbv[l], xB, Mrows, 3 * f, nin); }
      k_pool<<<gc, 256, 0, stream>>>(xB, L[l].p, pnm + l, xA, es, ed, em, z, nin, nout, g0);
      xin = xA;
    }
  }
  k_mlp<<<GG, 256, 0, stream>>>(z, l1w, l1b, l2w, l2b, out);
}

// Round 4
// 3804.827 us; speedup vs baseline: 1.1034x; 1.1034x over previous
//
#include <hip/hip_runtime.h>
#include <hip/hip_bf16.h>

#define GG 512
#define NMAX 256
#define EE 1024
#define HH 3
#define EMB 256
#define NEDGE 1280   // EE + NMAX
#define NEG 0.2f

// ---------------- prep kernels (per layer, tiny, run once) ----------------
__global__ void k_prep_wa(const float* __restrict__ W, const float* __restrict__ asrc,
                          const float* __restrict__ adst, float* __restrict__ wa_s,
                          float* __restrict__ wa_d, int f) {
  int t = blockIdx.x * blockDim.x + threadIdx.x;
  int tot = HH * f;
  if (t >= 2 * tot) return;
  int which = t / tot;
  int r = t - which * tot;
  int hd = r / f, ff = r - hd * f;
  const float* a = which ? adst : asrc;
  float s = 0.f;
  for (int c = 0; c < EMB; ++c)
    s += a[hd * EMB + c] * W[(size_t)(hd * EMB + c) * f + ff];
  (which ? wa_d : wa_s)[r] = s;
}

__global__ void k_prep_mcat(const float* __restrict__ W, const float* __restrict__ htw,
                            float* __restrict__ mcat, int f) {
  int t = blockIdx.x * blockDim.x + threadIdx.x;
  if (t >= 3 * f * EMB) return;
  int row = t / EMB, j = t - row * EMB;
  int hd = row / f, ff = row - hd * f;
  float s = 0.f;
  for (int c = 0; c < EMB; ++c)
    s += htw[(size_t)j * (HH * EMB) + hd * EMB + c] * W[(size_t)(hd * EMB + c) * f + ff];
  mcat[(size_t)row * EMB + j] = s;
}

__global__ void k_prep_bb(const float* __restrict__ b, const float* __restrict__ htw,
                          const float* __restrict__ htb, float* __restrict__ bb) {
  int j = threadIdx.x;
  float s = htb[j];
  for (int k = 0; k < HH * EMB; ++k) s += b[k] * htw[(size_t)j * (HH * EMB) + k];
  bb[j] = s;
}

__global__ void k_prep_pnorm(const float* __restrict__ p, double* __restrict__ pnorm) {
  __shared__ double sh[256];
  int t = threadIdx.x;
  double v = (double)p[t];
  sh[t] = v * v;
  __syncthreads();
  for (int s = 128; s > 0; s >>= 1) { if (t < s) sh[t] += sh[t + s]; __syncthreads(); }
  if (t == 0) pnorm[0] = sqrt(sh[0]);
}

// ---------------- per-chunk edge init ----------------
__global__ void k_initedges(const int* __restrict__ s_in, const int* __restrict__ d_in_,
                            int* __restrict__ es, int* __restrict__ ed,
                            int* __restrict__ em, int gc) {
  int t = blockIdx.x * blockDim.x + threadIdx.x;
  if (t >= gc * EE) return;
  es[t] = s_in[t]; ed[t] = d_in_[t]; em[t] = 1;
}

// ---------------- attention coefficients a_s, a_d ----------------
__global__ __launch_bounds__(256) void k_attn(
    const float* __restrict__ x, const float* __restrict__ wa_s,
    const float* __restrict__ wa_d, float* __restrict__ a_s,
    float* __restrict__ a_d, int gc, int n_in, int f) {
  int t = blockIdx.x * blockDim.x + threadIdx.x;
  if (t >= gc * n_in) return;
  int g = t / n_in, i = t - g * n_in;
  const float* xr = x + ((size_t)g * NMAX + i) * f;
  float s0 = 0, s1 = 0, s2 = 0, d0 = 0, d1 = 0, d2 = 0;
  for (int c = 0; c < f; ++c) {
    float xv = xr[c];
    s0 += xv * wa_s[0 * f + c]; s1 += xv * wa_s[1 * f + c]; s2 += xv * wa_s[2 * f + c];
    d0 += xv * wa_d[0 * f + c]; d1 += xv * wa_d[1 * f + c]; d2 += xv * wa_d[2 * f + c];
  }
  float* as = a_s + ((size_t)g * NMAX + i) * HH;
  float* ad = a_d + ((size_t)g * NMAX + i) * HH;
  as[0] = s0; as[1] = s1; as[2] = s2; ad[0] = d0; ad[1] = d1; ad[2] = d2;
}

// ---------------- edge logits (valid edges + self loops) ----------------
__global__ __launch_bounds__(256) void k_logit(
    const int* __restrict__ es, const int* __restrict__ ed,
    const int* __restrict__ em, const float* __restrict__ a_s,
    const float* __restrict__ a_d, float* __restrict__ lg, int gc, int n_in) {
  int etot = EE + n_in;
  int t = blockIdx.x * blockDim.x + threadIdx.x;
  if (t >= gc * etot) return;
  int g = t / etot, e = t - g * etot;
  int s, d, v;
  if (e < EE) { s = es[g * EE + e]; d = ed[g * EE + e]; v = em[g * EE + e]; }
  else { s = d = e - EE; v = 1; }
  if (!v) return;
  const float* as = a_s + ((size_t)g * NMAX + s) * HH;
  const float* ad = a_d + ((size_t)g * NMAX + d) * HH;
  float* o = lg + ((size_t)g * NEDGE + e) * HH;
#pragma unroll
  for (int hd = 0; hd < HH; ++hd) {
    float lv = as[hd] + ad[hd];
    o[hd] = lv > 0.f ? lv : NEG * lv;
  }
}

// ---------------- deterministic CSR by destination (one block per graph) ----------------
__global__ void k_csr(const int* __restrict__ ed, const int* __restrict__ em,
                      int* __restrict__ coff, int* __restrict__ elist, int n_in) {
  __shared__ unsigned short sdst[NEDGE];
  __shared__ unsigned char sval[NEDGE];
  __shared__ int cnt[257];
  int g = blockIdx.x, tid = threadIdx.x;
  int etot = EE + n_in;
  cnt[tid] = 0;
  if (tid == 0) cnt[256] = 0;
  __syncthreads();
  for (int e = tid; e < etot; e += 256) {
    int d, v;
    if (e < EE) { d = ed[g * EE + e]; v = em[g * EE + e]; }
    else { d = e - EE; v = 1; }
    sdst[e] = (unsigned short)d; sval[e] = (unsigned char)v;
    if (v) atomicAdd(&cnt[d], 1);
  }
  __syncthreads();
  if (tid == 0) {
    int run = 0;
    for (int i = 0; i < n_in; ++i) {
      int c = cnt[i]; cnt[i] = run; coff[g * 257 + i] = run; run += c;
    }
    coff[g * 257 + n_in] = run;
  }
  __syncthreads();
  if (tid < n_in) {
    int pos = cnt[tid];
    for (int e = 0; e < etot; ++e) {
      if (sval[e] && sdst[e] == (unsigned short)tid) elist[g * NEDGE + pos++] = e;
    }
  }
}

// ---------------- per-destination softmax + feature aggregation (one wave per dst) -----
__global__ __launch_bounds__(256) void k_gather(
    const float* __restrict__ x, const float* __restrict__ lg,
    const int* __restrict__ es, const int* __restrict__ elist,
    const int* __restrict__ coff, float* __restrict__ agg,
    int gc, int n_in, int f) {
  int wid = (blockIdx.x * blockDim.x + threadIdx.x) >> 6;
  int lane = threadIdx.x & 63;
  if (wid >= gc * n_in) return;
  int g = wid / n_in, dst = wid - g * n_in;
  int o0 = coff[g * 257 + dst], o1 = coff[g * 257 + dst + 1];
  float m0 = -1e30f, m1 = -1e30f, m2 = -1e30f;
  for (int t = o0; t < o1; ++t) {
    int e = elist[g * NEDGE + t];
    const float* l = lg + ((size_t)g * NEDGE + e) * HH;
    m0 = fmaxf(m0, l[0]); m1 = fmaxf(m1, l[1]); m2 = fmaxf(m2, l[2]);
  }
  float den0 = 0, den1 = 0, den2 = 0;
  if (f == 256) {
    // vectorized path: one float4 per lane (64*4 = 256)
    float4 acc0 = make_float4(0, 0, 0, 0);
    float4 acc1 = make_float4(0, 0, 0, 0);
    float4 acc2 = make_float4(0, 0, 0, 0);
    for (int t = o0; t < o1; ++t) {
      int e = elist[g * NEDGE + t];
      const float* l = lg + ((size_t)g * NEDGE + e) * HH;
      float w0 = expf(l[0] - m0), w1 = expf(l[1] - m1), w2 = expf(l[2] - m2);
      den0 += w0; den1 += w1; den2 += w2;
      int src = e < EE ? es[g * EE + e] : (e - EE);
      const float4* xr = (const float4*)(x + ((size_t)g * NMAX + src) * 256);
      float4 v = xr[lane];
      acc0.x += w0 * v.x; acc0.y += w0 * v.y; acc0.z += w0 * v.z; acc0.w += w0 * v.w;
      acc1.x += w1 * v.x; acc1.y += w1 * v.y; acc1.z += w1 * v.z; acc1.w += w1 * v.w;
      acc2.x += w2 * v.x; acc2.y += w2 * v.y; acc2.z += w2 * v.z; acc2.w += w2 * v.w;
    }
    float* ar = agg + ((size_t)g * n_in + dst) * (HH * 256);
    float r0 = 1.f / den0, r1 = 1.f / den1, r2 = 1.f / den2;
    float4 o;
    o.x = acc0.x * r0; o.y = acc0.y * r0; o.z = acc0.z * r0; o.w = acc0.w * r0;
    ((float4*)(ar + 0 * 256))[lane] = o;
    o.x = acc1.x * r1; o.y = acc1.y * r1; o.z = acc1.z * r1; o.w = acc1.w * r1;
    ((float4*)(ar + 1 * 256))[lane] = o;
    o.x = acc2.x * r2; o.y = acc2.y * r2; o.z = acc2.z * r2; o.w = acc2.w * r2;
    ((float4*)(ar + 2 * 256))[lane] = o;
  } else {
    float acc[HH][4];
#pragma unroll
    for (int hd = 0; hd < HH; ++hd)
#pragma unroll
      for (int j = 0; j < 4; ++j) acc[hd][j] = 0.f;
    int vpl = (f + 63) >> 6;
    for (int t = o0; t < o1; ++t) {
      int e = elist[g * NEDGE + t];
      const float* l = lg + ((size_t)g * NEDGE + e) * HH;
      float w0 = expf(l[0] - m0), w1 = expf(l[1] - m1), w2 = expf(l[2] - m2);
      den0 += w0; den1 += w1; den2 += w2;
      int src = e < EE ? es[g * EE + e] : (e - EE);
      const float* xr = x + ((size_t)g * NMAX + src) * f;
      for (int j = 0; j < vpl; ++j) {
        int c = lane + (j << 6);
        float xv = (c < f) ? xr[c] : 0.f;
        acc[0][j] += w0 * xv; acc[1][j] += w1 * xv; acc[2][j] += w2 * xv;
      }
    }
    float* ar = agg + ((size_t)g * n_in + dst) * (HH * f);
    float r0 = 1.f / den0, r1 = 1.f / den1, r2 = 1.f / den2;
    for (int j = 0; j < vpl; ++j) {
      int c = lane + (j << 6);
      if (c < f) {
        ar[0 * f + c] = acc[0][j] * r0;
        ar[1 * f + c] = acc[1][j] * r1;
        ar[2 * f + c] = acc[2][j] * r2;
      }
    }
  }
}

// ---------------- fp32 GEMM: Xout = A[Mrows,K] @ B[K,256] + bias ----------------
// BM=128, BN=256 (full N in one block -> A fetched exactly once), BK=16.
// 256 threads, 8x16 outputs each. Bank-conflict-free LDS layout:
//  - A frags: 4 broadcast addresses per wave (ty in 0..3), stride 32 B -> conflict-free
//  - B frags: 8x ds_read_b64, 16 lanes at 8 B stride span exactly 128 B -> conflict-free
#define GBM 128
#define GBK 16
#define ALD 136   // padded LDS stride (floats), 544 B, 16B-aligned
#define BLD 264   // padded LDS stride (floats), 1056 B, 16B-aligned
__global__ __launch_bounds__(256) void k_gemm(
    const float* __restrict__ A, const float* __restrict__ B,
    const float* __restrict__ bias, float* __restrict__ Xout,
    int Mrows, int K, int n_in) {
  __shared__ float As[GBK][ALD];
  __shared__ float Bs[GBK][BLD];
  int tid = threadIdx.x;
  int tx = tid & 15, ty = tid >> 4;
  int row0 = blockIdx.x * GBM;
  float acc[8][16];
#pragma unroll
  for (int i = 0; i < 8; ++i)
#pragma unroll
    for (int j = 0; j < 16; ++j) acc[i][j] = 0.f;

  for (int k0 = 0; k0 < K; k0 += GBK) {
    // ---- stage A tile [128 x 16] (transposed into As[k][m]) ----
    {
      int m = tid >> 2, kq = (tid & 3) << 2;
#pragma unroll
      for (int h = 0; h < 2; ++h) {
        int mm = m + h * 64;
        int row = row0 + mm;
        float v0 = 0.f, v1 = 0.f, v2 = 0.f, v3 = 0.f;
        if (row < Mrows) {
          if (k0 + kq + 3 < K) {
            float4 v = *(const float4*)&A[(size_t)row * K + k0 + kq];
            v0 = v.x; v1 = v.y; v2 = v.z; v3 = v.w;
          } else {
            if (k0 + kq + 0 < K) v0 = A[(size_t)row * K + k0 + kq + 0];
            if (k0 + kq + 1 < K) v1 = A[(size_t)row * K + k0 + kq + 1];
            if (k0 + kq + 2 < K) v2 = A[(size_t)row * K + k0 + kq + 2];
            if (k0 + kq + 3 < K) v3 = A[(size_t)row * K + k0 + kq + 3];
          }
        }
        As[kq + 0][mm] = v0; As[kq + 1][mm] = v1;
        As[kq + 2][mm] = v2; As[kq + 3][mm] = v3;
      }
    }
    // ---- stage B tile [16 x 256] ----
    {
      int kk = tid >> 4;
      int c0 = tx << 4;
      if (k0 + kk < K) {
        const float* br = &B[(size_t)(k0 + kk) * EMB + c0];
#pragma unroll
        for (int q = 0; q < 4; ++q)
          *(float4*)&Bs[kk][c0 + q * 4] = *(const float4*)&br[q * 4];
      } else {
#pragma unroll
        for (int q = 0; q < 4; ++q)
          *(float4*)&Bs[kk][c0 + q * 4] = make_float4(0, 0, 0, 0);
      }
    }
    __syncthreads();
#pragma unroll
    for (int kk = 0; kk < GBK; ++kk) {
      float a[8], b[16];
      float4 a0 = *(const float4*)&As[kk][ty * 8];
      float4 a1 = *(const float4*)&As[kk][ty * 8 + 4];
      a[0] = a0.x; a[1] = a0.y; a[2] = a0.z; a[3] = a0.w;
      a[4] = a1.x; a[5] = a1.y; a[6] = a1.z; a[7] = a1.w;
#pragma unroll
      for (int jj = 0; jj < 8; ++jj) {
        float2 bv = *(const float2*)&Bs[kk][tx * 2 + jj * 32];
        b[jj * 2] = bv.x; b[jj * 2 + 1] = bv.y;
      }
#pragma unroll
      for (int i = 0; i < 8; ++i)
#pragma unroll
        for (int j = 0; j < 16; ++j) acc[i][j] += a[i] * b[j];
    }
    __syncthreads();
  }
  // ---- epilogue: bias + write (cols tx*2 + jj*32, float2, coalesced) ----
  float2 bi[8];
#pragma unroll
  for (int jj = 0; jj < 8; ++jj) bi[jj] = *(const float2*)&bias[tx * 2 + jj * 32];
#pragma unroll
  for (int i = 0; i < 8; ++i) {
    int r = row0 + ty * 8 + i;
    if (r >= Mrows) continue;
    int g = r / n_in, ii = r - g * n_in;
    float* orow = Xout + ((size_t)g * NMAX + ii) * EMB;
#pragma unroll
    for (int jj = 0; jj < 8; ++jj) {
      float2 v;
      v.x = acc[i][jj * 2] + bi[jj].x;
      v.y = acc[i][jj * 2 + 1] + bi[jj].y;
      *(float2*)&orow[tx * 2 + jj * 32] = v;
    }
  }
}

// ---------------- TopK pool + readout + edge remap (one block per chunk-graph) --------
__global__ void k_pool(const float* __restrict__ xin, const float* __restrict__ p,
                       const double* __restrict__ pnorm, float* __restrict__ xout,
                       int* __restrict__ es, int* __restrict__ ed, int* __restrict__ em,
                       float* __restrict__ z, int n_in, int k, int g0) {
  __shared__ unsigned long long keys[256];
  __shared__ float ssc[256];
  __shared__ int inv[256];
  int g = blockIdx.x, tid = threadIdx.x;
  double pn = pnorm[0];
  float sc = -3e38f;
  if (tid < n_in) {
    const float* xr = xin + ((size_t)g * NMAX + tid) * EMB;
    double s = 0.0;
    for (int c = 0; c < EMB; ++c) s += (double)xr[c] * (double)p[c];
    sc = (float)tanh(s / pn);
  }
  ssc[tid] = sc;
  unsigned int u = __float_as_uint(sc);
  unsigned int ord = (u & 0x80000000u) ? ~u : (u | 0x80000000u);
  unsigned long long key = ((unsigned long long)(~ord) << 32) | (unsigned int)tid;
  if (tid >= n_in) key = 0xFFFFFFFF00000000ull | (unsigned int)tid;
  keys[tid] = key;
  __syncthreads();
  for (int kk = 2; kk <= 256; kk <<= 1) {
    for (int j = kk >> 1; j > 0; j >>= 1) {
      int ixj = tid ^ j;
      if (ixj > tid) {
        unsigned long long a = keys[tid], b = keys[ixj];
        bool up = ((tid & kk) == 0);
        if (up ? (a > b) : (a < b)) { keys[tid] = b; keys[ixj] = a; }
      }
      __syncthreads();
    }
  }
  inv[tid] = -1;
  __syncthreads();
  if (tid < k) inv[(int)(keys[tid] & 0xFFFFu)] = tid;
  __syncthreads();
  float mx = -3e38f, sm = 0.f;
  for (int j = 0; j < k; ++j) {
    int pi = (int)(keys[j] & 0xFFFFu);
    float val = ssc[pi];
    float v = xin[((size_t)g * NMAX + pi) * EMB + tid] * val;
    xout[((size_t)g * NMAX + j) * EMB + tid] = v;
    mx = fmaxf(mx, v);
    sm += v;
  }
  z[(size_t)(g0 + g) * (2 * EMB) + tid] += mx;
  z[(size_t)(g0 + g) * (2 * EMB) + EMB + tid] += sm / (float)k;
  for (int e = tid; e < EE; e += 256) {
    int s = es[g * EE + e], d = ed[g * EE + e], m = em[g * EE + e];
    int ns = inv[s], nd = inv[d];
    int nm = (m && ns >= 0 && nd >= 0) ? 1 : 0;
    es[g * EE + e] = ns < 0 ? 0 : ns;
    ed[g * EE + e] = nd < 0 ? 0 : nd;
    em[g * EE + e] = nm;
  }
}

// ---------------- final MLP ----------------
__global__ void k_mlp(const float* __restrict__ z, const float* __restrict__ l1w,
                      const float* __restrict__ l1b, const float* __restrict__ l2w,
                      const float* __restrict__ l2b, float* __restrict__ out) {
  __shared__ float zs[512];
  __shared__ float h1[256];
  int g = blockIdx.x, tid = threadIdx.x;
  zs[tid] = z[(size_t)g * 512 + tid];
  zs[256 + tid] = z[(size_t)g * 512 + 256 + tid];
  __syncthreads();
  float s = l1b[tid];
  for (int c = 0; c < 512; ++c) s += zs[c] * l1w[(size_t)tid * 512 + c];
  h1[tid] = s > 0.f ? s : 0.f;
  __syncthreads();
  if (tid < 2) {
    float o = l2b[tid];
    for (int c = 0; c < 256; ++c) o += h1[c] * l2w[(size_t)tid * 256 + c];
    out[g * 2 + tid] = o;
  }
}

extern "C" void kernel_launch(void* const* d_in, const int* in_sizes, int n_in_cnt,
                              void* d_out, int out_size, void* d_ws, size_t ws_size,
                              hipStream_t stream) {
  (void)in_sizes; (void)n_in_cnt; (void)out_size;
  const float* x0 = (const float*)d_in[0];
  const int* e_src = (const int*)d_in[1];
  const int* e_dst = (const int*)d_in[2];
  struct LP { const float *W, *as, *ad, *b, *hw, *hb, *p; int f, nin, nout; };
  LP L[3];
  for (int l = 0; l < 3; ++l) {
    int base = 3 + l * 7;
    L[l].W  = (const float*)d_in[base + 0];
    L[l].as = (const float*)d_in[base + 1];
    L[l].ad = (const float*)d_in[base + 2];
    L[l].b  = (const float*)d_in[base + 3];
    L[l].hw = (const float*)d_in[base + 4];
    L[l].hb = (const float*)d_in[base + 5];
    L[l].p  = (const float*)d_in[base + 6];
  }
  L[0].f = 30;  L[1].f = 256; L[2].f = 256;
  L[0].nin = 256; L[0].nout = 205;
  L[1].nin = 205; L[1].nout = 164;
  L[2].nin = 164; L[2].nout = 132;
  const float* l1w = (const float*)d_in[24];
  const float* l1b = (const float*)d_in[25];
  const float* l2w = (const float*)d_in[26];
  const float* l2b = (const float*)d_in[27];
  float* out = (float*)d_out;

  char* w = (char*)d_ws;
  char* wend = w + ws_size;
  auto alloc = [&](size_t bytes) {
    char* r = w; w += (bytes + 255) & ~(size_t)255; return r;
  };
  // ---- fixed buffers ----
  float*  z    = (float*)alloc((size_t)GG * 512 * 4);
  float*  wa_s[3]; float* wa_d[3]; float* mcat[3]; float* bbv[3];
  for (int l = 0; l < 3; ++l) {
    wa_s[l] = (float*)alloc((size_t)HH * 256 * 4);
    wa_d[l] = (float*)alloc((size_t)HH * 256 * 4);
    mcat[l] = (float*)alloc((size_t)HH * 256 * EMB * 4);
    bbv[l]  = (float*)alloc((size_t)EMB * 4);
  }
  double* pnm = (double*)alloc(256);

  // ---- adaptive chunk size ----
  size_t fixed_used = (size_t)(w - (char*)d_ws);
  size_t per_g = 0;
  {
    auto pad = [](size_t b) { return (b + 255) & ~(size_t)255; };
    per_g = pad((size_t)NMAX * EMB * 4) * 2          // xA, xB
          + pad((size_t)NMAX * HH * EMB * 4)         // agg (256*768 f32)
          + pad((size_t)NMAX * HH * 4) * 2           // a_s, a_d
          + pad((size_t)NEDGE * HH * 4)              // lg
          + pad((size_t)EE * 4) * 3                  // es, ed, em
          + pad((size_t)257 * 4)                     // coff
          + pad((size_t)NEDGE * 4);                  // elist
    per_g += 11 * 256;                               // alignment slop
  }
  size_t avail = (ws_size > fixed_used + 65536) ? (ws_size - fixed_used - 65536) : 0;
  int Gc = (int)(avail / per_g);
  if (Gc > GG) Gc = GG;
  if (Gc < 1) Gc = 1;

  // ---- per-chunk buffers (sized for Gc graphs) ----
  float* xA   = (float*)alloc((size_t)Gc * NMAX * EMB * 4);
  float* xB   = (float*)alloc((size_t)Gc * NMAX * EMB * 4);
  float* agg  = (float*)alloc((size_t)Gc * NMAX * HH * EMB * 4);
  float* a_s  = (float*)alloc((size_t)Gc * NMAX * HH * 4);
  float* a_d  = (float*)alloc((size_t)Gc * NMAX * HH * 4);
  float* lg   = (float*)alloc((size_t)Gc * NEDGE * HH * 4);
  int*   es   = (int*)alloc((size_t)Gc * EE * 4);
  int*   ed   = (int*)alloc((size_t)Gc * EE * 4);
  int*   em   = (int*)alloc((size_t)Gc * EE * 4);
  int*   coff = (int*)alloc((size_t)Gc * 257 * 4);
  int*   elist= (int*)alloc((size_t)Gc * NEDGE * 4);
  if (w > wend) return;  // avoid OOB launches entirely

  (void)hipMemsetAsync(z, 0, (size_t)GG * 512 * 4, stream);

  // ---- per-layer prep (once) ----
  for (int l = 0; l < 3; ++l) {
    int f = L[l].f;
    k_prep_wa<<<(2 * HH * f + 255) / 256, 256, 0, stream>>>(L[l].W, L[l].as, L[l].ad, wa_s[l], wa_d[l], f);
    k_prep_mcat<<<(3 * f * EMB + 255) / 256, 256, 0, stream>>>(L[l].W, L[l].hw, mcat[l], f);
    k_prep_bb<<<1, 256, 0, stream>>>(L[l].b, L[l].hw, L[l].hb, bbv[l]);
    k_prep_pnorm<<<1, 256, 0, stream>>>(L[l].p, pnm + l);
  }

  // ---- chunked pipeline over graphs ----
  for (int g0 = 0; g0 < GG; g0 += Gc) {
    int gc = (GG - g0 < Gc) ? (GG - g0) : Gc;
    { int tot = gc * EE;
      k_initedges<<<(tot + 255) / 256, 256, 0, stream>>>(e_src + (size_t)g0 * EE, e_dst + (size_t)g0 * EE, es, ed, em, gc); }
    const float* xin = x0 + (size_t)g0 * NMAX * 30;  // layer-0 input (f=30)
    for (int l = 0; l < 3; ++l) {
      int f = L[l].f, nin = L[l].nin, nout = L[l].nout;
      k_attn<<<(gc * nin + 255) / 256, 256, 0, stream>>>(xin, wa_s[l], wa_d[l], a_s, a_d, gc, nin, f);
      { int tot = gc * (EE + nin);
        k_logit<<<(tot + 255) / 256, 256, 0, stream>>>(es, ed, em, a_s, a_d, lg, gc, nin); }
      k_csr<<<gc, 256, 0, stream>>>(ed, em, coff, elist, nin);
      { int waves = gc * nin;
        k_gather<<<(waves * 64 + 255) / 256, 256, 0, stream>>>(xin, lg, es, elist, coff, agg, gc, nin, f); }
      { int Mrows = gc * nin;
        dim3 gemm_grid((Mrows + GBM - 1) / GBM);
        k_gemm<<<gemm_grid, 256, 0, stream>>>(agg, mcat[l], bbv[l], xB, Mrows, 3 * f, nin); }
      k_pool<<<gc, 256, 0, stream>>>(xB, L[l].p, pnm + l, xA, es, ed, em, z, nin, nout, g0);
      xin = xA;
    }
  }
  k_mlp<<<GG, 256, 0, stream>>>(z, l1w, l1b, l2w, l2b, out);
}